// Round 1
// 604.516 us; speedup vs baseline: 1.0839x; 1.0839x over previous
//
#include <hip/hip_runtime.h>
#include <math.h>

// Problem constants (fixed shapes from setup_inputs):
//   x [4,2048,4096] f32, W [4096,4096] f32, bias [4096] f32,
//   lora_A [16,4096] f32, lora_B [4096,16] f32, out [8192,4096] f32
#define MDIM 8192
#define NDIM 4096
#define KDIM 4096

typedef __attribute__((ext_vector_type(8))) _Float16 h8;
typedef __attribute__((ext_vector_type(4))) _Float16 h4;
typedef __attribute__((ext_vector_type(4))) float f32x4;

typedef const __attribute__((address_space(1))) void* gas_ptr;
typedef __attribute__((address_space(3))) void* las_ptr;

__device__ inline void load16_to_lds(const void* g, void* l) {
  // async global->LDS, 16B/lane; LDS dest = wave-uniform base + lane*16
  __builtin_amdgcn_global_load_lds((gas_ptr)g, (las_ptr)l, 16, 0, 0);
}

// ---------- 4x4 double helpers ----------
__device__ inline void mm4(const double* A, const double* B, double* C) {
#pragma unroll
  for (int p = 0; p < 4; ++p)
#pragma unroll
    for (int q = 0; q < 4; ++q) {
      double s = 0.0;
#pragma unroll
      for (int r = 0; r < 4; ++r) s += A[p * 4 + r] * B[r * 4 + q];
      C[p * 4 + q] = s;
    }
}
__device__ inline void mm4_bt(const double* A, const double* B, double* C) {
  // C = A * B^T
#pragma unroll
  for (int p = 0; p < 4; ++p)
#pragma unroll
    for (int q = 0; q < 4; ++q) {
      double s = 0.0;
#pragma unroll
      for (int r = 0; r < 4; ++r) s += A[p * 4 + r] * B[q * 4 + r];
      C[p * 4 + q] = s;
    }
}

// ---------- kernel 1: Gu/Gv reductions + factored Newton-Schulz ----------
__global__ void ns_kernel(const float* __restrict__ lora_A,
                          const float* __restrict__ lora_B,
                          float* __restrict__ E) {
  const int h = blockIdx.x;
  const int tid = threadIdx.x;
  const int lane = tid & 63;
  const int wave = tid >> 6;

  float gu[16], gv[16];
#pragma unroll
  for (int e = 0; e < 16; ++e) { gu[e] = 0.f; gv[e] = 0.f; }

  for (int o = tid; o < NDIM; o += 256) {
    const float4 bv = *(const float4*)(lora_B + (size_t)o * 16 + h * 4);
    const float bb[4] = {bv.x, bv.y, bv.z, bv.w};
#pragma unroll
    for (int p = 0; p < 4; ++p)
#pragma unroll
      for (int q = 0; q < 4; ++q) gu[p * 4 + q] += bb[p] * bb[q];
  }
  for (int i = tid; i < KDIM; i += 256) {
    float aa[4];
#pragma unroll
    for (int p = 0; p < 4; ++p) aa[p] = lora_A[(size_t)(h * 4 + p) * KDIM + i];
#pragma unroll
    for (int p = 0; p < 4; ++p)
#pragma unroll
      for (int q = 0; q < 4; ++q) gv[p * 4 + q] += aa[p] * aa[q];
  }

#pragma unroll
  for (int e = 0; e < 16; ++e) {
#pragma unroll
    for (int off = 32; off > 0; off >>= 1) {
      gu[e] += __shfl_down(gu[e], off, 64);
      gv[e] += __shfl_down(gv[e], off, 64);
    }
  }
  __shared__ float pu[4][16], pv[4][16];
  if (lane == 0) {
#pragma unroll
    for (int e = 0; e < 16; ++e) { pu[wave][e] = gu[e]; pv[wave][e] = gv[e]; }
  }
  __syncthreads();

  if (tid == 0) {
    double gud[16], gvd[16];
#pragma unroll
    for (int e = 0; e < 16; ++e) {
      gud[e] = (double)pu[0][e] + pu[1][e] + pu[2][e] + pu[3][e];
      gvd[e] = (double)pv[0][e] + pv[1][e] + pv[2][e] + pv[3][e];
    }
    double tr = 0.0;
#pragma unroll
    for (int e = 0; e < 16; ++e) tr += gud[e] * gvd[e];
    const double alpha = sqrt(tr);
    const double n0 = alpha + 1e-7;

    double C[16] = {0};
    C[0] = C[5] = C[10] = C[15] = 1.0 / n0;

    const double a = 3.4445, b = -4.775, c = 2.0315;
    for (int it = 0; it < 5; ++it) {
      double T1[16], D[16], DG[16], DGD[16], GuC[16], F[16], Cn[16];
      mm4(C, gvd, T1);
      mm4_bt(T1, C, D);
      mm4(D, gud, DG);
      mm4(DG, D, DGD);
      mm4(gud, C, GuC);
#pragma unroll
      for (int e = 0; e < 16; ++e) F[e] = b * D[e] + c * DGD[e];
      mm4(F, GuC, Cn);
#pragma unroll
      for (int e = 0; e < 16; ++e) C[e] = a * C[e] + Cn[e];
    }
#pragma unroll
    for (int e = 0; e < 16; ++e) E[h * 16 + e] = (float)(alpha * C[e]);
  }
}

// ---------- kernel 2 (fused): blocks [0,4096) build Weff; [4096,20480) cast x ----------
__global__ void prep_kernel(const float* __restrict__ x,
                            const float* __restrict__ W,
                            const float* __restrict__ lora_A,
                            const float* __restrict__ lora_B,
                            const float* __restrict__ E,
                            _Float16* __restrict__ Wh,
                            _Float16* __restrict__ Xh) {
  const int tid = threadIdx.x;
  if (blockIdx.x < NDIM) {
    const int o = blockIdx.x;
    __shared__ float coef[16];
    if (tid < 16) {
      const int h = tid >> 2, q = tid & 3;
      float s = 0.f;
#pragma unroll
      for (int p = 0; p < 4; ++p)
        s += lora_B[(size_t)o * 16 + h * 4 + p] * E[h * 16 + p * 4 + q];
      coef[tid] = s;
    }
    __syncthreads();
    float cf[16];
#pragma unroll
    for (int k = 0; k < 16; ++k) cf[k] = coef[k];

    for (int i = tid * 4; i < KDIM; i += 1024) {
      float4 acc = *(const float4*)(W + (size_t)o * KDIM + i);
#pragma unroll
      for (int k = 0; k < 16; ++k) {
        const float4 av = *(const float4*)(lora_A + (size_t)k * KDIM + i);
        acc.x += cf[k] * av.x; acc.y += cf[k] * av.y;
        acc.z += cf[k] * av.z; acc.w += cf[k] * av.w;
      }
      h4 pk;
      pk[0] = (_Float16)acc.x; pk[1] = (_Float16)acc.y;
      pk[2] = (_Float16)acc.z; pk[3] = (_Float16)acc.w;
      *(h4*)(Wh + (size_t)o * KDIM + i) = pk;
    }
  } else {
    const size_t t = (size_t)(blockIdx.x - NDIM) * 256 + tid;
    const size_t base = t * 8;
    const float4 a = *(const float4*)(x + base);
    const float4 b = *(const float4*)(x + base + 4);
    h8 o;
    o[0] = (_Float16)a.x; o[1] = (_Float16)a.y; o[2] = (_Float16)a.z; o[3] = (_Float16)a.w;
    o[4] = (_Float16)b.x; o[5] = (_Float16)b.y; o[6] = (_Float16)b.z; o[7] = (_Float16)b.w;
    *(h8*)(Xh + base) = o;
  }
}

// ---------- kernel 3: 256x256 8-phase pipelined GEMM (T1+T2+T3+T4+T5) ----------
// out[m][n] = sum_k Xh[m][k]*Wh[n][k] + bias[n]
// 512 threads = 8 waves (wm=wave>>2 in {0,1}, wn=wave&3 in {0..3}).
// Wave output: rows {mq*128 + wm*64 .. +64} x cols {nq*128 + wn*32 .. +32}, mq,nq in {0,1}
// => quadrant (mq,nq) reads ONLY A-half mq and B-half nq. Quadrant order
// (0,0),(0,1),(1,0),(1,1) frees A0 after phase1, B0 after phase2 => stage schedule:
//   q0: stage A1(t+1) -> other-buf, q1: B1(t+1) -> other-buf,
//   q2: A0(t+2) -> cur-buf (A0(t) dead), q3: B0(t+2) -> cur-buf (B0(t) dead).
// vmcnt(4) once per K-tile (2 half-tiles = 4 loads stay in flight); never 0 in steady state.
// LDS: 8 distinct 16KB arrays (so alias analysis can't force spurious vmcnt drains).
// Swizzle: stored chunk s holds logical k-chunk s^(row&7); applied on the pre-swizzled
// GLOBAL source (global_load_lds dest must stay linear base+lane*16), undone on ds_read.
__launch_bounds__(512, 2)
__global__ void gemm_kernel(const _Float16* __restrict__ Xh,   // [M][K]
                            const _Float16* __restrict__ Wh,   // [N][K]
                            const float* __restrict__ bias,
                            float* __restrict__ out) {         // [M][N]
  __shared__ __align__(16) _Float16 sA0h0[128 * 64], sA0h1[128 * 64];
  __shared__ __align__(16) _Float16 sA1h0[128 * 64], sA1h1[128 * 64];
  __shared__ __align__(16) _Float16 sB0h0[128 * 64], sB0h1[128 * 64];
  __shared__ __align__(16) _Float16 sB1h0[128 * 64], sB1h1[128 * 64];

  const int tid = threadIdx.x;
  const int lane = tid & 63;
  const int wave = tid >> 6;
  const int wm = wave >> 2;       // 0..1
  const int wn = wave & 3;        // 0..3
  const int quad = lane >> 4;     // k-chunk selector
  const int r16 = lane & 15;      // row within 16x16 fragment
  const int sw = r16 & 7;         // read-side swizzle key (row&7 == r16&7 here)

  // XCD-aware swizzle: 512 wgs, 8 XCDs, 64 contiguous wgs per XCD (same bm-panel group)
  const int lin = blockIdx.x;
  const int wg = (lin & 7) * 64 + (lin >> 3);
  const int bm = wg >> 4;  // 0..31
  const int bn = wg & 15;  // 0..15

  // staging: each thread loads chunks tid and tid+512 of a 128x(64f16) half-tile.
  // chunk c: row=c>>3 (row-in-half), stored slot sc=c&7 holds logical chunk sc^(row&7).
  const int row0 = tid >> 3;                    // 0..63 (second load: +64, same swizzle)
  const int lc0 = (tid & 7) ^ (row0 & 7);
  const size_t off0 = (size_t)row0 * KDIM + lc0 * 8;
  const int ldsb = tid * 16;
  const _Float16* pA0 = Xh + (size_t)(bm * 256) * KDIM;
  const _Float16* pA1 = pA0 + (size_t)128 * KDIM;
  const _Float16* pB0 = Wh + (size_t)(bn * 256) * KDIM;
  const _Float16* pB1 = pB0 + (size_t)128 * KDIM;

  // compute-side LDS element offsets (row*64 + stored_chunk*8)
  const int aRow = (wm * 64 + r16) * 64;
  const int bRow = (wn * 32 + r16) * 64;
  const int c0 = (quad ^ sw) * 8;        // ks=0: logical chunk quad
  const int c1 = ((quad + 4) ^ sw) * 8;  // ks=1: logical chunk quad+4

  f32x4 acc[2][2][4][2] = {};

#define STAGE(arr, p, koff) do {                                               \
    load16_to_lds((p) + off0 + (koff), (char*)(arr) + ldsb);                   \
    load16_to_lds((p) + off0 + (size_t)64 * KDIM + (koff),                     \
                  (char*)(arr) + ldsb + 8192);                                 \
  } while (0)

#define FENCE() asm volatile("" ::: "memory")
#define BAR() do { FENCE(); __builtin_amdgcn_s_barrier(); FENCE(); } while (0)
#define VM4() asm volatile("s_waitcnt vmcnt(4)" ::: "memory")
#define VM0() asm volatile("s_waitcnt vmcnt(0)" ::: "memory")

#define PHASE(Aarr, Barr, mq, nq, STMT, WCNT) do {                             \
    h8 av[4][2], bv[2][2];                                                     \
    _Pragma("unroll")                                                          \
    for (int f = 0; f < 4; ++f) {                                              \
      av[f][0] = *(const h8*)&Aarr[aRow + f * 1024 + c0];                      \
      av[f][1] = *(const h8*)&Aarr[aRow + f * 1024 + c1];                      \
    }                                                                          \
    _Pragma("unroll")                                                          \
    for (int g = 0; g < 2; ++g) {                                              \
      bv[g][0] = *(const h8*)&Barr[bRow + g * 1024 + c0];                      \
      bv[g][1] = *(const h8*)&Barr[bRow + g * 1024 + c1];                      \
    }                                                                          \
    STMT;                                                                      \
    BAR();                                                                     \
    __builtin_amdgcn_s_setprio(1);                                             \
    _Pragma("unroll")                                                          \
    for (int f = 0; f < 4; ++f)                                                \
      _Pragma("unroll")                                                        \
      for (int g = 0; g < 2; ++g) {                                            \
        acc[mq][nq][f][g] = __builtin_amdgcn_mfma_f32_16x16x32_f16(            \
            av[f][0], bv[g][0], acc[mq][nq][f][g], 0, 0, 0);                   \
        acc[mq][nq][f][g] = __builtin_amdgcn_mfma_f32_16x16x32_f16(            \
            av[f][1], bv[g][1], acc[mq][nq][f][g], 0, 0, 0);                   \
      }                                                                        \
    __builtin_amdgcn_s_setprio(0);                                             \
    WCNT;                                                                      \
    BAR();                                                                     \
  } while (0)

// cur-buf arrays (cA0,cA1,cB0,cB1); other-buf h1 targets (oA1,oB1) for tile t+1;
// tile t+2 has same parity as t -> its A0/B0 go into cA0/cB0.
#define TILE(t, cA0, cA1, cB0, cB1, oA1, oB1) do {                             \
    PHASE(cA0, cB0, 0, 0,                                                      \
          { if ((t) + 1 < NT) STAGE(oA1, pA1, ((t) + 1) * 64); }, ;);          \
    PHASE(cA0, cB1, 0, 1,                                                      \
          { if ((t) + 1 < NT) STAGE(oB1, pB1, ((t) + 1) * 64); }, ;);          \
    PHASE(cA1, cB0, 1, 0,                                                      \
          { if ((t) + 2 < NT) STAGE(cA0, pA0, ((t) + 2) * 64); }, ;);          \
    PHASE(cA1, cB1, 1, 1,                                                      \
          { if ((t) + 2 < NT) STAGE(cB0, pB0, ((t) + 2) * 64); },              \
          { if ((t) + 2 < NT) VM4(); else VM0(); });                           \
  } while (0)

  constexpr int NT = KDIM / 64;  // 64 K-tiles

  // prologue: tile0 fully + tile1 A0,B0 (12 loads); leave last 4 in flight
  STAGE(sA0h0, pA0, 0);  STAGE(sB0h0, pB0, 0);
  STAGE(sA0h1, pA1, 0);  STAGE(sB0h1, pB1, 0);
  STAGE(sA1h0, pA0, 64); STAGE(sB1h0, pB0, 64);
  VM4();
  BAR();

#pragma unroll 1
  for (int t2 = 0; t2 < NT; t2 += 2) {
    TILE(t2,     sA0h0, sA0h1, sB0h0, sB0h1, sA1h1, sB1h1);
    TILE(t2 + 1, sA1h0, sA1h1, sB1h0, sB1h1, sA0h1, sB0h1);
  }

  // epilogue: D row=(lane>>4)*4+reg (M side), col=lane&15 (N side)
#pragma unroll
  for (int mq = 0; mq < 2; ++mq)
#pragma unroll
    for (int f = 0; f < 4; ++f) {
      float* po = out + (size_t)(bm * 256 + mq * 128 + wm * 64 + f * 16 + quad * 4) * NDIM;
#pragma unroll
      for (int nq = 0; nq < 2; ++nq)
#pragma unroll
        for (int g = 0; g < 2; ++g) {
          const int ocol = bn * 256 + nq * 128 + wn * 32 + g * 16 + r16;
          const float bb = bias[ocol];
          const f32x4 v = acc[mq][nq][f][g];
#pragma unroll
          for (int rg = 0; rg < 4; ++rg)
            po[(size_t)rg * NDIM + ocol] = v[rg] + bb;
        }
    }
}

extern "C" void kernel_launch(void* const* d_in, const int* in_sizes, int n_in,
                              void* d_out, int out_size, void* d_ws, size_t ws_size,
                              hipStream_t stream) {
  const float* x      = (const float*)d_in[0];  // [8192,4096]
  const float* W      = (const float*)d_in[1];  // [4096,4096]
  const float* bias   = (const float*)d_in[2];  // [4096]
  const float* lora_A = (const float*)d_in[3];  // [16,4096]
  const float* lora_B = (const float*)d_in[4];  // [4096,16]
  float* out = (float*)d_out;

  char* ws = (char*)d_ws;
  float* E = (float*)ws;                                     // 64 floats
  _Float16* Wh = (_Float16*)(ws + 1024);                     // 4096*4096*2 B
  _Float16* Xh = (_Float16*)(ws + 1024 + (size_t)NDIM * KDIM * 2);  // 8192*4096*2 B

  ns_kernel<<<dim3(4), dim3(256), 0, stream>>>(lora_A, lora_B, E);
  prep_kernel<<<dim3(NDIM + (MDIM * KDIM) / (256 * 8)), dim3(256), 0, stream>>>(
      x, W, lora_A, lora_B, E, Wh, Xh);
  gemm_kernel<<<dim3(512), dim3(512), 0, stream>>>(Xh, Wh, bias, out);
}

// Round 2
// 602.915 us; speedup vs baseline: 1.0868x; 1.0027x over previous
//
#include <hip/hip_runtime.h>
#include <math.h>

// Problem constants (fixed shapes from setup_inputs):
//   x [4,2048,4096] f32, W [4096,4096] f32, bias [4096] f32,
//   lora_A [16,4096] f32, lora_B [4096,16] f32, out [8192,4096] f32
#define MDIM 8192
#define NDIM 4096
#define KDIM 4096

typedef __attribute__((ext_vector_type(8))) _Float16 h8;
typedef __attribute__((ext_vector_type(4))) _Float16 h4;
typedef __attribute__((ext_vector_type(4))) float f32x4;

typedef const __attribute__((address_space(1))) void* gas_ptr;
typedef __attribute__((address_space(3))) void* las_ptr;

__device__ inline void load16_to_lds(const void* g, void* l) {
  // async global->LDS, 16B/lane; LDS dest = wave-uniform base + lane*16
  __builtin_amdgcn_global_load_lds((gas_ptr)g, (las_ptr)l, 16, 0, 0);
}

// ---------- 4x4 double helpers ----------
__device__ inline void mm4(const double* A, const double* B, double* C) {
#pragma unroll
  for (int p = 0; p < 4; ++p)
#pragma unroll
    for (int q = 0; q < 4; ++q) {
      double s = 0.0;
#pragma unroll
      for (int r = 0; r < 4; ++r) s += A[p * 4 + r] * B[r * 4 + q];
      C[p * 4 + q] = s;
    }
}
__device__ inline void mm4_bt(const double* A, const double* B, double* C) {
  // C = A * B^T
#pragma unroll
  for (int p = 0; p < 4; ++p)
#pragma unroll
    for (int q = 0; q < 4; ++q) {
      double s = 0.0;
#pragma unroll
      for (int r = 0; r < 4; ++r) s += A[p * 4 + r] * B[q * 4 + r];
      C[p * 4 + q] = s;
    }
}

// ---------- kernel 1: Gu/Gv reductions + factored Newton-Schulz ----------
__global__ void ns_kernel(const float* __restrict__ lora_A,
                          const float* __restrict__ lora_B,
                          float* __restrict__ E) {
  const int h = blockIdx.x;
  const int tid = threadIdx.x;
  const int lane = tid & 63;
  const int wave = tid >> 6;

  float gu[16], gv[16];
#pragma unroll
  for (int e = 0; e < 16; ++e) { gu[e] = 0.f; gv[e] = 0.f; }

  for (int o = tid; o < NDIM; o += 256) {
    const float4 bv = *(const float4*)(lora_B + (size_t)o * 16 + h * 4);
    const float bb[4] = {bv.x, bv.y, bv.z, bv.w};
#pragma unroll
    for (int p = 0; p < 4; ++p)
#pragma unroll
      for (int q = 0; q < 4; ++q) gu[p * 4 + q] += bb[p] * bb[q];
  }
  for (int i = tid; i < KDIM; i += 256) {
    float aa[4];
#pragma unroll
    for (int p = 0; p < 4; ++p) aa[p] = lora_A[(size_t)(h * 4 + p) * KDIM + i];
#pragma unroll
    for (int p = 0; p < 4; ++p)
#pragma unroll
      for (int q = 0; q < 4; ++q) gv[p * 4 + q] += aa[p] * aa[q];
  }

#pragma unroll
  for (int e = 0; e < 16; ++e) {
#pragma unroll
    for (int off = 32; off > 0; off >>= 1) {
      gu[e] += __shfl_down(gu[e], off, 64);
      gv[e] += __shfl_down(gv[e], off, 64);
    }
  }
  __shared__ float pu[4][16], pv[4][16];
  if (lane == 0) {
#pragma unroll
    for (int e = 0; e < 16; ++e) { pu[wave][e] = gu[e]; pv[wave][e] = gv[e]; }
  }
  __syncthreads();

  if (tid == 0) {
    double gud[16], gvd[16];
#pragma unroll
    for (int e = 0; e < 16; ++e) {
      gud[e] = (double)pu[0][e] + pu[1][e] + pu[2][e] + pu[3][e];
      gvd[e] = (double)pv[0][e] + pv[1][e] + pv[2][e] + pv[3][e];
    }
    double tr = 0.0;
#pragma unroll
    for (int e = 0; e < 16; ++e) tr += gud[e] * gvd[e];
    const double alpha = sqrt(tr);
    const double n0 = alpha + 1e-7;

    double C[16] = {0};
    C[0] = C[5] = C[10] = C[15] = 1.0 / n0;

    const double a = 3.4445, b = -4.775, c = 2.0315;
    for (int it = 0; it < 5; ++it) {
      double T1[16], D[16], DG[16], DGD[16], GuC[16], F[16], Cn[16];
      mm4(C, gvd, T1);
      mm4_bt(T1, C, D);
      mm4(D, gud, DG);
      mm4(DG, D, DGD);
      mm4(gud, C, GuC);
#pragma unroll
      for (int e = 0; e < 16; ++e) F[e] = b * D[e] + c * DGD[e];
      mm4(F, GuC, Cn);
#pragma unroll
      for (int e = 0; e < 16; ++e) C[e] = a * C[e] + Cn[e];
    }
#pragma unroll
    for (int e = 0; e < 16; ++e) E[h * 16 + e] = (float)(alpha * C[e]);
  }
}

// ---------- kernel 2 (fused): blocks [0,256) build Weff (16 rows/block, lora_A
// chunk staged in LDS -> lora_A global traffic 1GB->64MB); [256,16640) cast x ----------
__global__ void prep_kernel(const float* __restrict__ x,
                            const float* __restrict__ W,
                            const float* __restrict__ lora_A,
                            const float* __restrict__ lora_B,
                            const float* __restrict__ E,
                            _Float16* __restrict__ Wh,
                            _Float16* __restrict__ Xh) {
  const int tid = threadIdx.x;
  if (blockIdx.x < 256) {
    __shared__ float cf[16][16];                 // [row r][k] combination coeffs
    __shared__ __align__(16) float Asm[16][1024];  // 64KB lora_A chunk
    const int o0 = blockIdx.x * 16;
    {
      const int r = tid >> 4, kk = tid & 15, h = kk >> 2, q = kk & 3;
      float s = 0.f;
#pragma unroll
      for (int p = 0; p < 4; ++p)
        s += lora_B[(size_t)(o0 + r) * 16 + h * 4 + p] * E[h * 16 + p * 4 + q];
      cf[r][kk] = s;
    }
    for (int kb = 0; kb < KDIM; kb += 1024) {
      __syncthreads();  // prev chunk's Asm readers done (also publishes cf, iter 0)
#pragma unroll
      for (int j = 0; j < 16; ++j) {
        const int f4 = tid + j * 256;  // 0..4095 float4s, fully coalesced
        const int k = f4 >> 8, c4 = f4 & 255;
        *(float4*)&Asm[k][c4 * 4] =
            *(const float4*)&lora_A[(size_t)k * KDIM + kb + (size_t)c4 * 4];
      }
      __syncthreads();
      float4 av[16];
#pragma unroll
      for (int k = 0; k < 16; ++k) av[k] = *(const float4*)&Asm[k][tid * 4];
#pragma unroll
      for (int r = 0; r < 16; ++r) {
        const size_t base = (size_t)(o0 + r) * KDIM + kb + tid * 4;
        float4 acc = *(const float4*)&W[base];
#pragma unroll
        for (int k = 0; k < 16; ++k) {
          const float cfv = cf[r][k];  // LDS broadcast
          acc.x += cfv * av[k].x; acc.y += cfv * av[k].y;
          acc.z += cfv * av[k].z; acc.w += cfv * av[k].w;
        }
        h4 pk;
        pk[0] = (_Float16)acc.x; pk[1] = (_Float16)acc.y;
        pk[2] = (_Float16)acc.z; pk[3] = (_Float16)acc.w;
        *(h4*)(Wh + base) = pk;
      }
    }
  } else {
    const size_t t = (size_t)(blockIdx.x - 256) * 256 + tid;
    const size_t base = t * 8;
    const float4 a = *(const float4*)(x + base);
    const float4 b = *(const float4*)(x + base + 4);
    h8 o;
    o[0] = (_Float16)a.x; o[1] = (_Float16)a.y; o[2] = (_Float16)a.z; o[3] = (_Float16)a.w;
    o[4] = (_Float16)b.x; o[5] = (_Float16)b.y; o[6] = (_Float16)b.z; o[7] = (_Float16)b.w;
    *(h8*)(Xh + base) = o;
  }
}

// ---------- kernel 3: 256x256 8-phase pipelined GEMM ----------
// Zigzag quadrant order (0,0)->(0,1)->(1,1)->(1,0): consecutive phases share one
// operand in registers -> ds_reads/tile 48->28 (per-phase 12,4,8,4), putting LDS
// time (768,256,512,256 cyc) below/at MFMA time (515 cyc) for 3 of 4 phases.
// Stage schedule (all into other-parity buffers of tile t+1):
//   ph0: A0(t+1)  ph1: B0(t+1)  ph2: B1(t+1)  ph3: A1(t+1)
// vmcnt(4) before the end-barrier of phases 0,1,3 (none at ph2):
//   end ph3(t-1): drains A0(t),B0(t)  -> ph0 reads safe
//   end ph0(t):   drains B1(t)        -> ph1 safe
//   end ph1(t):   drains A1(t)        -> ph2 safe   (ph3 re-reads B0: already drained)
// Every load has >=2.75 phases (~1600cyc) in flight before its drain point.
__launch_bounds__(512, 2)
__global__ void gemm_kernel(const _Float16* __restrict__ Xh,   // [M][K]
                            const _Float16* __restrict__ Wh,   // [N][K]
                            const float* __restrict__ bias,
                            float* __restrict__ out) {         // [M][N]
  __shared__ __align__(16) _Float16 sA0_0[128 * 64], sA0_1[128 * 64];
  __shared__ __align__(16) _Float16 sA1_0[128 * 64], sA1_1[128 * 64];
  __shared__ __align__(16) _Float16 sB0_0[128 * 64], sB0_1[128 * 64];
  __shared__ __align__(16) _Float16 sB1_0[128 * 64], sB1_1[128 * 64];

  const int tid = threadIdx.x;
  const int lane = tid & 63;
  const int wave = tid >> 6;
  const int wm = wave >> 2;       // 0..1
  const int wn = wave & 3;        // 0..3
  const int quad = lane >> 4;     // k-chunk selector
  const int r16 = lane & 15;      // row within 16x16 fragment
  const int sw = r16 & 7;         // read-side swizzle key

  // XCD-aware swizzle: 512 wgs, 8 XCDs, 64 contiguous wgs per XCD
  const int lin = blockIdx.x;
  const int wg = (lin & 7) * 64 + (lin >> 3);
  const int bm = wg >> 4;  // 0..31
  const int bn = wg & 15;  // 0..15

  // staging: chunk c of a 128x(64f16) half-tile: row=c>>3, stored slot s=c&7
  // holds logical chunk s^(row&7) (swizzle applied on pre-swizzled global source)
  const int row0 = tid >> 3;
  const int lc0 = (tid & 7) ^ (row0 & 7);
  const size_t off0 = (size_t)row0 * KDIM + lc0 * 8;
  const int ldsb = tid * 16;
  const _Float16* pA0 = Xh + (size_t)(bm * 256) * KDIM;
  const _Float16* pA1 = pA0 + (size_t)128 * KDIM;
  const _Float16* pB0 = Wh + (size_t)(bn * 256) * KDIM;
  const _Float16* pB1 = pB0 + (size_t)128 * KDIM;

  // compute-side LDS element offsets
  const int aRow = (wm * 64 + r16) * 64;
  const int bRow = (wn * 32 + r16) * 64;
  const int c0 = (quad ^ sw) * 8;
  const int c1 = ((quad + 4) ^ sw) * 8;

  f32x4 acc[2][2][4][2] = {};
  h8 a0[4][2], a1[4][2], b0[2][2], b1[2][2];

#define STAGE(arr, p, koff) do {                                               \
    load16_to_lds((p) + off0 + (koff), (char*)(arr) + ldsb);                   \
    load16_to_lds((p) + off0 + (size_t)64 * KDIM + (koff),                     \
                  (char*)(arr) + ldsb + 8192);                                 \
  } while (0)

#define FENCE() asm volatile("" ::: "memory")
#define BAR() do { FENCE(); __builtin_amdgcn_s_barrier(); FENCE(); } while (0)
#define VM4() asm volatile("s_waitcnt vmcnt(4)" ::: "memory")
#define VM2() asm volatile("s_waitcnt vmcnt(2)" ::: "memory")
#define VM0() asm volatile("s_waitcnt vmcnt(0)" ::: "memory")

#define RDA(dst, Aarr) do { _Pragma("unroll")                                  \
    for (int f = 0; f < 4; ++f) {                                              \
      dst[f][0] = *(const h8*)&Aarr[aRow + f * 1024 + c0];                     \
      dst[f][1] = *(const h8*)&Aarr[aRow + f * 1024 + c1];                     \
    } } while (0)
#define RDB(dst, Barr) do { _Pragma("unroll")                                  \
    for (int g = 0; g < 2; ++g) {                                              \
      dst[g][0] = *(const h8*)&Barr[bRow + g * 1024 + c0];                     \
      dst[g][1] = *(const h8*)&Barr[bRow + g * 1024 + c1];                     \
    } } while (0)

#define MFMA16(MQ, NQ, AV, BV) do {                                            \
    __builtin_amdgcn_s_setprio(1);                                             \
    _Pragma("unroll")                                                          \
    for (int f = 0; f < 4; ++f)                                                \
      _Pragma("unroll")                                                        \
      for (int g = 0; g < 2; ++g) {                                            \
        acc[MQ][NQ][f][g] = __builtin_amdgcn_mfma_f32_16x16x32_f16(            \
            AV[f][0], BV[g][0], acc[MQ][NQ][f][g], 0, 0, 0);                   \
        acc[MQ][NQ][f][g] = __builtin_amdgcn_mfma_f32_16x16x32_f16(            \
            AV[f][1], BV[g][1], acc[MQ][NQ][f][g], 0, 0, 0);                   \
      }                                                                        \
    __builtin_amdgcn_s_setprio(0);                                             \
  } while (0)

#define TILE(t, cA0, cA1, cB0, cB1, nA0, nA1, nB0, nB1) do {                   \
    RDA(a0, cA0); RDB(b0, cB0); STAGE(nA0, pA0, ((t) + 1) * 64);               \
    BAR(); MFMA16(0, 0, a0, b0); VM4(); BAR();                                 \
    RDB(b1, cB1);                STAGE(nB0, pB0, ((t) + 1) * 64);              \
    BAR(); MFMA16(0, 1, a0, b1); VM4(); BAR();                                 \
    RDA(a1, cA1);                STAGE(nB1, pB1, ((t) + 1) * 64);              \
    BAR(); MFMA16(1, 1, a1, b1);        BAR();                                 \
    RDB(b0, cB0);                STAGE(nA1, pA1, ((t) + 1) * 64);              \
    BAR(); MFMA16(1, 0, a1, b0); VM4(); BAR();                                 \
  } while (0)

#define TILE_LAST(cA0, cA1, cB0, cB1) do {                                     \
    RDA(a0, cA0); RDB(b0, cB0);                                                \
    BAR(); MFMA16(0, 0, a0, b0); VM2(); BAR();                                 \
    RDB(b1, cB1);                                                              \
    BAR(); MFMA16(0, 1, a0, b1); VM0(); BAR();                                 \
    RDA(a1, cA1);                                                              \
    BAR(); MFMA16(1, 1, a1, b1);        BAR();                                 \
    RDB(b0, cB0);                                                              \
    BAR(); MFMA16(1, 0, a1, b0);        BAR();                                 \
  } while (0)

  constexpr int NT = KDIM / 64;  // 64 K-tiles

  // prologue: stage tile0 in the read order A0,B0,B1,A1; drain A0,B0; keep B1,A1 in flight
  STAGE(sA0_0, pA0, 0);
  STAGE(sB0_0, pB0, 0);
  STAGE(sB1_0, pB1, 0);
  STAGE(sA1_0, pA1, 0);
  VM4();
  BAR();

#pragma unroll 1
  for (int t2 = 0; t2 < NT - 2; t2 += 2) {
    TILE(t2,     sA0_0, sA1_0, sB0_0, sB1_0, sA0_1, sA1_1, sB0_1, sB1_1);
    TILE(t2 + 1, sA0_1, sA1_1, sB0_1, sB1_1, sA0_0, sA1_0, sB0_0, sB1_0);
  }
  TILE(NT - 2, sA0_0, sA1_0, sB0_0, sB1_0, sA0_1, sA1_1, sB0_1, sB1_1);
  TILE_LAST(sA0_1, sA1_1, sB0_1, sB1_1);

  // epilogue: D row=(lane>>4)*4+reg (M side), col=lane&15 (N side)
#pragma unroll
  for (int mq = 0; mq < 2; ++mq)
#pragma unroll
    for (int f = 0; f < 4; ++f) {
      float* po = out + (size_t)(bm * 256 + mq * 128 + wm * 64 + f * 16 + quad * 4) * NDIM;
#pragma unroll
      for (int nq = 0; nq < 2; ++nq)
#pragma unroll
        for (int g = 0; g < 2; ++g) {
          const int ocol = bn * 256 + nq * 128 + wn * 32 + g * 16 + r16;
          const float bb = bias[ocol];
          const f32x4 v = acc[mq][nq][f][g];
#pragma unroll
          for (int rg = 0; rg < 4; ++rg)
            po[(size_t)rg * NDIM + ocol] = v[rg] + bb;
        }
    }
}

extern "C" void kernel_launch(void* const* d_in, const int* in_sizes, int n_in,
                              void* d_out, int out_size, void* d_ws, size_t ws_size,
                              hipStream_t stream) {
  const float* x      = (const float*)d_in[0];  // [8192,4096]
  const float* W      = (const float*)d_in[1];  // [4096,4096]
  const float* bias   = (const float*)d_in[2];  // [4096]
  const float* lora_A = (const float*)d_in[3];  // [16,4096]
  const float* lora_B = (const float*)d_in[4];  // [4096,16]
  float* out = (float*)d_out;

  char* ws = (char*)d_ws;
  float* E = (float*)ws;                                     // 64 floats
  _Float16* Wh = (_Float16*)(ws + 1024);                     // 4096*4096*2 B
  _Float16* Xh = (_Float16*)(ws + 1024 + (size_t)NDIM * KDIM * 2);  // 8192*4096*2 B

  ns_kernel<<<dim3(4), dim3(256), 0, stream>>>(lora_A, lora_B, E);
  prep_kernel<<<dim3(256 + (MDIM * KDIM) / (256 * 8)), dim3(256), 0, stream>>>(
      x, W, lora_A, lora_B, E, Wh, Xh);
  gemm_kernel<<<dim3(512), dim3(512), 0, stream>>>(Xh, Wh, bias, out);
}